// Round 13
// baseline (968.912 us; speedup 1.0000x reference)
//
#include <hip/hip_runtime.h>
#include <hip/hip_bf16.h>

// BiRNN: T=512, B=64, NI=NH=512.
// out = [outputs (512*64*1024) | f_H (64*512) | b_H (64*512)] fp32.
//
// r13 = r12 with the per-step s_barrier replaced by LDS dataflow sync:
//   - 4-deep h ring buffer hq[4][8192] (32KB LDS)
//   - wpos[16]: publish flags (h(s) written) ; consumer polls all >= s
//   - rpos[16]: read flags (step-s A-reads retired); producer of h(s)
//     polls all >= s-3 before overwriting buf[s&3] (WAR, ring depth 4)
//   Waves self-skew -> MFMA/VALU/LDS pipes overlap instead of phase-locking.
//
// Permuted layout (per direction): chunk(t,rg,w) of 512 elems, w 0..15:
//   elem slot = ((t*4+rg)*16 + w)*512 + l*8 + n*4 + q
//   <-> value for batch row rg*16 + (l>>4)*4 + q, col w*32 + n*16 + (l&15)

typedef __attribute__((ext_vector_type(8))) short short8;   // 8 bf16 (4 VGPR)
typedef __attribute__((ext_vector_type(4))) float f32x4;
typedef __attribute__((ext_vector_type(4))) int   i32x4;    // 16 i8 (4 VGPR)

static __device__ __forceinline__ unsigned short f2bf(float f) {
  unsigned int u = __builtin_bit_cast(unsigned int, f);
  u = (u + 0x7fffu + ((u >> 16) & 1u)) >> 16;   // RNE
  return (unsigned short)u;
}
static __device__ __forceinline__ float bf2f(unsigned short s) {
  return __builtin_bit_cast(float, ((unsigned int)s) << 16);
}
// tanh = 1 - 2/(2^(x*2log2e) + 1); raw HW exp/rcp (~1 ulp each, exact at +-inf)
static __device__ __forceinline__ float tanh_cheap(float x) {
  float t = x * 2.8853900817779268f;   // 2*log2(e)
  float e;
  asm("v_exp_f32 %0, %1" : "=v"(e) : "v"(t));
  float den = e + 1.0f;
  float r;
  asm("v_rcp_f32 %0, %1" : "=v"(r) : "v"(den));
  return __builtin_fmaf(-2.0f, r, 1.0f);
}
// D = {lo: bf16(a), hi: bf16(b)}  (RNE)
static __device__ __forceinline__ unsigned int cvt_pk_bf16(float a, float b) {
  unsigned int d;
  asm("v_cvt_pk_bf16_f32 %0, %1, %2" : "=v"(d) : "v"(a), "v"(b));
  return d;
}

// ---------------------------------------------------------------------------
// Kernel 1: xw GEMM -> permuted layout (512-elem chunks), bias folded in.
// (unchanged from r12)
// ---------------------------------------------------------------------------
__global__ __launch_bounds__(256, 2) void xw_gemm(
    const float* __restrict__ inp,       // [32768][512]
    const float* __restrict__ Wf,        // [512][512]
    const float* __restrict__ Wb,        // [512][512]
    const float* __restrict__ bhf,       // [512]
    const float* __restrict__ bhb,       // [512]
    unsigned short* __restrict__ xwpf,   // permuted bf16 (xw + bias)
    unsigned short* __restrict__ xwpb) {
  __shared__ unsigned short As[64 * 40];
  __shared__ unsigned short Bfs[64 * 40];
  __shared__ unsigned short Bbs[64 * 40];
  const int tid = threadIdx.x;
  const int w = tid >> 6, l = tid & 63;
  const int lr = l & 15, lg = l >> 4;
  const int rbase = blockIdx.x * 64;
  const int nbase = blockIdx.y * 64;

  f32x4 accf[4], accb[4];
#pragma unroll
  for (int tn = 0; tn < 4; ++tn) { accf[tn] = (f32x4){0,0,0,0}; accb[tn] = (f32x4){0,0,0,0}; }

  for (int i = 0; i < 16; ++i) {
    const int k0 = i * 32;
    __syncthreads();
#pragma unroll
    for (int e = 0; e < 2; ++e) {
      int lin4 = tid + e * 256;
      int r = lin4 >> 3, c4 = (lin4 & 7) * 4;
      float4 v = *reinterpret_cast<const float4*>(&inp[(rbase + r) * 512 + k0 + c4]);
      unsigned short* dst = &As[r * 40 + c4];
      dst[0] = f2bf(v.x); dst[1] = f2bf(v.y); dst[2] = f2bf(v.z); dst[3] = f2bf(v.w);
    }
#pragma unroll
    for (int e = 0; e < 2; ++e) {
      int lin4 = tid + e * 256;
      int r = lin4 >> 4, c4 = (lin4 & 15) * 4;
      float4 vf = *reinterpret_cast<const float4*>(&Wf[(k0 + r) * 512 + nbase + c4]);
      float4 vb = *reinterpret_cast<const float4*>(&Wb[(k0 + r) * 512 + nbase + c4]);
      Bfs[(c4 + 0) * 40 + r] = f2bf(vf.x);
      Bfs[(c4 + 1) * 40 + r] = f2bf(vf.y);
      Bfs[(c4 + 2) * 40 + r] = f2bf(vf.z);
      Bfs[(c4 + 3) * 40 + r] = f2bf(vf.w);
      Bbs[(c4 + 0) * 40 + r] = f2bf(vb.x);
      Bbs[(c4 + 1) * 40 + r] = f2bf(vb.y);
      Bbs[(c4 + 2) * 40 + r] = f2bf(vb.z);
      Bbs[(c4 + 3) * 40 + r] = f2bf(vb.w);
    }
    __syncthreads();
    const int ar = w * 16 + lr;
    const int kg = lg * 8;
    short8 a = *reinterpret_cast<const short8*>(&As[ar * 40 + kg]);
#pragma unroll
    for (int tn = 0; tn < 4; ++tn) {
      const int bc = tn * 16 + lr;
      short8 bf = *reinterpret_cast<const short8*>(&Bfs[bc * 40 + kg]);
      short8 bb = *reinterpret_cast<const short8*>(&Bbs[bc * 40 + kg]);
      accf[tn] = __builtin_amdgcn_mfma_f32_16x16x32_bf16(a, bf, accf[tn], 0, 0, 0);
      accb[tn] = __builtin_amdgcn_mfma_f32_16x16x32_bf16(a, bb, accb[tn], 0, 0, 0);
    }
  }
  unsigned long long* pf = reinterpret_cast<unsigned long long*>(xwpf);
  unsigned long long* pb = reinterpret_cast<unsigned long long*>(xwpb);
  const int b64 = (((int)blockIdx.x * 4 + w) * 16 + (int)blockIdx.y * 2) * 128 +
                  (lg * 16 + lr) * 2;
#pragma unroll
  for (int tn = 0; tn < 4; ++tn) {
    const int colb = nbase + tn * 16 + lr;
    const float bfv = bhf[colb], bbv = bhb[colb];
    unsigned long long vf =
        (unsigned long long)cvt_pk_bf16(accf[tn][0] + bfv, accf[tn][1] + bfv)
      | ((unsigned long long)cvt_pk_bf16(accf[tn][2] + bfv, accf[tn][3] + bfv) << 32);
    unsigned long long vb =
        (unsigned long long)cvt_pk_bf16(accb[tn][0] + bbv, accb[tn][1] + bbv)
      | ((unsigned long long)cvt_pk_bf16(accb[tn][2] + bbv, accb[tn][3] + bbv) << 32);
    pf[b64 + (tn >> 1) * 128 + (tn & 1)] = vf;
    pb[b64 + (tn >> 1) * 128 + (tn & 1)] = vb;
  }
}

// ---------------------------------------------------------------------------
// Kernel 2: CU-local scan, 8 WGs x 1024 threads (16 waves, 4/SIMD).
// Dataflow-sync'd (no per-step barrier); 4-deep LDS h ring.
// ---------------------------------------------------------------------------
__global__ __launch_bounds__(1024) void birnn_scan(
    const float* __restrict__ Whf, const float* __restrict__ Whb,
    unsigned short* __restrict__ xwpf, unsigned short* __restrict__ xwpb,
    float* __restrict__ out) {
  const int bid = blockIdx.x;         // 0..7
  const int d  = bid >> 2;
  const int rg = bid & 3;
  const int tid = threadIdx.x;
  const int w = tid >> 6, l = tid & 63;      // w 0..15
  const int lr = l & 15, lg = l >> 4;
  const int cbase = w * 32;
  const int rbase = rg * 16;

  const float* Wh = d ? Whb : Whf;
  unsigned short* xwp = d ? xwpb : xwpf;

  // h ring, fragment-major i8: addr(row,k) = (k>>4)*256 + row*16 + (k&15)
  __shared__ __align__(16) signed char hq[4][8192];
  __shared__ int wpos[16];   // wave j published h(s)  -> wpos[j] = s+1
  __shared__ int rpos[16];   // wave j's step-s A-reads retired -> rpos[j] = s
  if (tid < 16) { wpos[tid] = 0; rpos[tid] = 0; }
  __syncthreads();

  // preload + quantize W_hh B-frags (k-bijection: k = kk*64 + lg*16 + j)
  const float sW = 127.0f / 0.06f;
  i32x4 wq[2][8];
#pragma unroll
  for (int n = 0; n < 2; ++n) {
    const int col = cbase + n * 16 + lr;
#pragma unroll
    for (int kk = 0; kk < 8; ++kk) {
      i32x4 v;
#pragma unroll
      for (int dw = 0; dw < 4; ++dw) {
        unsigned int pack = 0;
#pragma unroll
        for (int jj = 0; jj < 4; ++jj) {
          const int k = kk * 64 + lg * 16 + dw * 4 + jj;
          float wv = Wh[k * 512 + col] * sW;
          wv = fminf(fmaxf(wv, -127.f), 127.f);
          int q = (int)rintf(wv);
          pack |= ((unsigned int)(q & 0xff)) << (8 * jj);
        }
        v[dw] = (int)pack;
      }
      wq[n][kk] = v;
    }
  }
  const float inv_s = 1.0f / (127.0f * sW);

  // depth-2 prefetch buffers: one short8 (16B) per step
  short8 xA, xB;
  {
    const int t0 = d ? 511 : 0;
    xA = *reinterpret_cast<const short8*>(
        xwp + (((t0 * 4 + rg) * 16 + w) << 9) + (l << 3));
  }
  {
    const int t1 = d ? 510 : 1;
    xB = *reinterpret_cast<const short8*>(
        xwp + (((t1 * 4 + rg) * 16 + w) << 9) + (l << 3));
  }

  uint4 HP;   // packed bf16 h of previous step (8 values)

#define EPI(N, ACC, U0, U1, FINAL_)                                           \
  {                                                                           \
    float h0_ = tanh_cheap(fmaf((float)(ACC)[0], inv_s, bf2f((unsigned short)X[(N)*4+0]))); \
    float h1_ = tanh_cheap(fmaf((float)(ACC)[1], inv_s, bf2f((unsigned short)X[(N)*4+1]))); \
    float h2_ = tanh_cheap(fmaf((float)(ACC)[2], inv_s, bf2f((unsigned short)X[(N)*4+2]))); \
    float h3_ = tanh_cheap(fmaf((float)(ACC)[3], inv_s, bf2f((unsigned short)X[(N)*4+3]))); \
    signed char* hd_ = &hq[buf_][(w * 2 + (N)) * 256 + lg * 64 + lr];         \
    hd_[0]  = (signed char)(int)rintf(h0_ * 127.f);                           \
    hd_[16] = (signed char)(int)rintf(h1_ * 127.f);                           \
    hd_[32] = (signed char)(int)rintf(h2_ * 127.f);                           \
    hd_[48] = (signed char)(int)rintf(h3_ * 127.f);                           \
    U0 = cvt_pk_bf16(h0_, h1_);                                               \
    U1 = cvt_pk_bf16(h2_, h3_);                                               \
    if (FINAL_) {                                                             \
      float* fo_ = out + 33554432 + d * 32768 + (rbase + lg * 4) * 512 +      \
                   cbase + (N) * 16 + lr;                                     \
      fo_[0] = h0_; fo_[512] = h1_; fo_[1024] = h2_; fo_[1536] = h3_;         \
    }                                                                         \
  }

#define STEP(S, XARG, FINAL_)                                                 \
  do {                                                                        \
    const int s_ = (S);                                                       \
    const int t_ = d ? (511 - s_) : s_;                                       \
    const int buf_ = s_ & 3;                                                  \
    const int pb_ = (s_ - 1) & 3;                                             \
    short8& X = (XARG);                                                       \
    /* consumer wait: all 16 waves published h(s-1) */                        \
    while (true) {                                                            \
      int v_ = *(volatile int*)&wpos[l & 15];                                 \
      if (__ballot(v_ >= s_) == ~0ull) break;                                 \
      __builtin_amdgcn_s_sleep(1);                                            \
    }                                                                         \
    asm volatile("" ::: "memory");                                            \
    { /* deferred global store of h(s-1) */                                   \
      const int tp_ = d ? (t_ + 1) : (t_ - 1);                                \
      unsigned short* pw_ = xwp + (((tp_ * 4 + rg) * 16 + w) << 9) + (l << 3);\
      *reinterpret_cast<uint4*>(pw_) = HP;                                    \
    }                                                                         \
    i32x4 acc0 = (i32x4){0,0,0,0}, acc1 = (i32x4){0,0,0,0};                   \
    __builtin_amdgcn_s_setprio(1);                                            \
    { /* A-frag window kk=0..3: chunks (kk*4+lg)*256 */                       \
      const signed char* hb_ = &hq[pb_][lg * 256 + lr * 16];                  \
      i32x4 a0 = *(const i32x4*)(hb_ + 0);                                    \
      i32x4 a1 = *(const i32x4*)(hb_ + 1024);                                 \
      i32x4 a2 = *(const i32x4*)(hb_ + 2048);                                 \
      i32x4 a3 = *(const i32x4*)(hb_ + 3072);                                 \
      acc0 = __builtin_amdgcn_mfma_i32_16x16x64_i8(a0, wq[0][0], acc0, 0, 0, 0); \
      acc1 = __builtin_amdgcn_mfma_i32_16x16x64_i8(a0, wq[1][0], acc1, 0, 0, 0); \
      acc0 = __builtin_amdgcn_mfma_i32_16x16x64_i8(a1, wq[0][1], acc0, 0, 0, 0); \
      acc1 = __builtin_amdgcn_mfma_i32_16x16x64_i8(a1, wq[1][1], acc1, 0, 0, 0); \
      acc0 = __builtin_amdgcn_mfma_i32_16x16x64_i8(a2, wq[0][2], acc0, 0, 0, 0); \
      acc1 = __builtin_amdgcn_mfma_i32_16x16x64_i8(a2, wq[1][2], acc1, 0, 0, 0); \
      acc0 = __builtin_amdgcn_mfma_i32_16x16x64_i8(a3, wq[0][3], acc0, 0, 0, 0); \
      acc1 = __builtin_amdgcn_mfma_i32_16x16x64_i8(a3, wq[1][3], acc1, 0, 0, 0); \
    }                                                                         \
    { /* A-frag window kk=4..7 */                                             \
      const signed char* hb_ = &hq[pb_][(16 + lg) * 256 + lr * 16];           \
      i32x4 a0 = *(const i32x4*)(hb_ + 0);                                    \
      i32x4 a1 = *(const i32x4*)(hb_ + 1024);                                 \
      i32x4 a2 = *(const i32x4*)(hb_ + 2048);                                 \
      i32x4 a3 = *(const i32x4*)(hb_ + 3072);                                 \
      acc0 = __builtin_amdgcn_mfma_i32_16x16x64_i8(a0, wq[0][4], acc0, 0, 0, 0); \
      acc1 = __builtin_amdgcn_mfma_i32_16x16x64_i8(a0, wq[1][4], acc1, 0, 0, 0); \
      acc0 = __builtin_amdgcn_mfma_i32_16x16x64_i8(a1, wq[0][5], acc0, 0, 0, 0); \
      acc1 = __builtin_amdgcn_mfma_i32_16x16x64_i8(a1, wq[1][5], acc1, 0, 0, 0); \
      acc0 = __builtin_amdgcn_mfma_i32_16x16x64_i8(a2, wq[0][6], acc0, 0, 0, 0); \
      acc1 = __builtin_amdgcn_mfma_i32_16x16x64_i8(a2, wq[1][6], acc1, 0, 0, 0); \
      acc0 = __builtin_amdgcn_mfma_i32_16x16x64_i8(a3, wq[0][7], acc0, 0, 0, 0); \
      acc1 = __builtin_amdgcn_mfma_i32_16x16x64_i8(a3, wq[1][7], acc1, 0, 0, 0); \
    }                                                                         \
    __builtin_amdgcn_s_setprio(0);                                            \
    /* publish read-progress: my A-reads of buf[pb_] retired */               \
    asm volatile("s_waitcnt lgkmcnt(0)" ::: "memory");                        \
    if (l == 0) *(volatile int*)&rpos[w] = s_;                                \
    /* WAR wait: everyone done reading h(s-4) (same ring slot as h(s)) */     \
    if (s_ >= 4) {                                                            \
      while (true) {                                                          \
        int v_ = *(volatile int*)&rpos[l & 15];                               \
        if (__ballot(v_ >= s_ - 3) == ~0ull) break;                           \
        __builtin_amdgcn_s_sleep(1);                                          \
      }                                                                       \
      asm volatile("" ::: "memory");                                          \
    }                                                                         \
    EPI(0, acc0, HP.x, HP.y, FINAL_);                                         \
    EPI(1, acc1, HP.z, HP.w, FINAL_);                                         \
    /* publish h(s): i8 writes retired, then flag */                          \
    asm volatile("s_waitcnt lgkmcnt(0)" ::: "memory");                        \
    if (l == 0) *(volatile int*)&wpos[w] = s_ + 1;                            \
    { /* prefetch xw for step s+2 into X */                                   \
      const int tp2_ = d ? (t_ - 2) : (t_ + 2);                               \
      X = *reinterpret_cast<const short8*>(                                   \
          xwp + (((tp2_ * 4 + rg) * 16 + w) << 9) + (l << 3));                \
    }                                                                         \
  } while (0)

  // step 0: h0 = 0 -> acc = 0, no MFMA, no waits
  {
    const int t_ = d ? 511 : 0;
    const int buf_ = 0;
    short8& X = xA;
    i32x4 z_ = (i32x4){0, 0, 0, 0};
    EPI(0, z_, HP.x, HP.y, 0);
    EPI(1, z_, HP.z, HP.w, 0);
    asm volatile("s_waitcnt lgkmcnt(0)" ::: "memory");
    if (l == 0) *(volatile int*)&wpos[w] = 1;
    {
      const int tp2_ = d ? (t_ - 2) : (t_ + 2);
      xA = *reinterpret_cast<const short8*>(
          xwp + (((tp2_ * 4 + rg) * 16 + w) << 9) + (l << 3));
    }
  }

  for (int ss = 0; ss < 255; ++ss) {
    STEP(1 + 2 * ss, xB, 0);
    STEP(2 + 2 * ss, xA, 0);
  }
  STEP(511, xB, 1);

  // store h(511)
  {
    const int tl_ = d ? 0 : 511;
    unsigned short* pw_ = xwp + (((tl_ * 4 + rg) * 16 + w) << 9) + (l << 3);
    *reinterpret_cast<uint4*>(pw_) = HP;
  }
#undef STEP
#undef EPI
}

// ---------------------------------------------------------------------------
// Kernel 3: expand h (bf16, permuted) -> fp32 outputs. (unchanged from r12)
// slot(t,b,col) = ((t*4+(b>>4))*16 + (col>>5))*512 +
//                 (((b>>2)&3)*16 + (col&15))*8 + ((col>>4)&1)*4 + (b&3)
// ---------------------------------------------------------------------------
__global__ __launch_bounds__(1024) void expand_out(
    const unsigned short* __restrict__ xwpf,
    const unsigned short* __restrict__ xwpb,
    float* __restrict__ out) {
  const int g = blockIdx.x * 1024 + threadIdx.x;   // 8,388,608 threads
  const int flat = g * 4;                          // 4 consecutive out elems
  const int row = flat >> 10;                      // t*64 + b
  const int c   = flat & 1023;
  const int t = row >> 6, b = row & 63;
  const int d = c >> 9, col = c & 511;
  const unsigned short* buf = d ? xwpb : xwpf;
  const int lr0 = col & 15;                        // 4-aligned, <=12
  const int base = ((t * 4 + (b >> 4)) * 16 + (col >> 5)) * 512 +
                   (((b >> 2) & 3) * 16) * 8 + ((col >> 4) & 1) * 4 + (b & 3);
  float4 v;
  v.x = bf2f(buf[base + (lr0 + 0) * 8]);
  v.y = bf2f(buf[base + (lr0 + 1) * 8]);
  v.z = bf2f(buf[base + (lr0 + 2) * 8]);
  v.w = bf2f(buf[base + (lr0 + 3) * 8]);
  *reinterpret_cast<float4*>(out + flat) = v;
}

// ---------------------------------------------------------------------------
extern "C" void kernel_launch(void* const* d_in, const int* in_sizes, int n_in,
                              void* d_out, int out_size, void* d_ws, size_t ws_size,
                              hipStream_t stream) {
  (void)in_sizes; (void)n_in; (void)out_size; (void)ws_size;
  const float* inputs = (const float*)d_in[0];
  const float* W_xh_f = (const float*)d_in[1];
  const float* W_hh_f = (const float*)d_in[2];
  const float* b_h_f  = (const float*)d_in[3];
  const float* W_xh_b = (const float*)d_in[4];
  const float* W_hh_b = (const float*)d_in[5];
  const float* b_h_b  = (const float*)d_in[6];

  // ws: [xwpf 16.78M elems][pad 64K elems][xwpb 16.78M elems][pad]  (bf16)
  // pads absorb depth-2 prefetch overruns (fwd t+2<=513; bwd t-2>=-2 reads
  // land in xwpf's pad region).
  unsigned short* xwpf = (unsigned short*)d_ws;
  unsigned short* xwpb = xwpf + 16777216 + 65536;

  dim3 g1(512, 8), b1(256);
  xw_gemm<<<g1, b1, 0, stream>>>(inputs, W_xh_f, W_xh_b, b_h_f, b_h_b, xwpf, xwpb);

  birnn_scan<<<dim3(8), dim3(1024), 0, stream>>>(
      W_hh_f, W_hh_b, xwpf, xwpb, (float*)d_out);

  expand_out<<<dim3(8192), dim3(1024), 0, stream>>>(xwpf, xwpb, (float*)d_out);
}

// Round 14
// 847.593 us; speedup vs baseline: 1.1431x; 1.1431x over previous
//
#include <hip/hip_runtime.h>
#include <hip/hip_bf16.h>

// BiRNN: T=512, B=64, NI=NH=512.
// out = [outputs (512*64*1024) | f_H (64*512) | b_H (64*512)] fp32.
//
// r14 = scan reverted to r12 exactly (659us proven; r13's dataflow sync
// regressed 19% -- all-to-all step dependency makes s_barrier optimal).
// GEMM staging rewritten: v_cvt_pk_bf16_f32 packed converts (1 inst/2 elems
// vs ~6/elem scalar RNE) + b64 vectorized A-tile LDS writes + occupancy 4.
//
// Permuted layout (per direction): chunk(t,rg,w) of 512 elems, w 0..15:
//   elem slot = ((t*4+rg)*16 + w)*512 + l*8 + n*4 + q
//   <-> value for batch row rg*16 + (l>>4)*4 + q, col w*32 + n*16 + (l&15)

typedef __attribute__((ext_vector_type(8))) short short8;   // 8 bf16 (4 VGPR)
typedef __attribute__((ext_vector_type(4))) float f32x4;
typedef __attribute__((ext_vector_type(4))) int   i32x4;    // 16 i8 (4 VGPR)

static __device__ __forceinline__ float bf2f(unsigned short s) {
  return __builtin_bit_cast(float, ((unsigned int)s) << 16);
}
// tanh = 1 - 2/(2^(x*2log2e) + 1); raw HW exp/rcp (~1 ulp each, exact at +-inf)
static __device__ __forceinline__ float tanh_cheap(float x) {
  float t = x * 2.8853900817779268f;   // 2*log2(e)
  float e;
  asm("v_exp_f32 %0, %1" : "=v"(e) : "v"(t));
  float den = e + 1.0f;
  float r;
  asm("v_rcp_f32 %0, %1" : "=v"(r) : "v"(den));
  return __builtin_fmaf(-2.0f, r, 1.0f);
}
// LDS-visibility-only barrier: does NOT drain vmcnt (global ops fly across).
static __device__ __forceinline__ void lds_barrier() {
  __builtin_amdgcn_sched_barrier(0);
  asm volatile("s_waitcnt lgkmcnt(0)" ::: "memory");
  __builtin_amdgcn_s_barrier();
  __builtin_amdgcn_sched_barrier(0);
}
// D = {lo: bf16(a), hi: bf16(b)}  (RNE)
static __device__ __forceinline__ unsigned int cvt_pk_bf16(float a, float b) {
  unsigned int d;
  asm("v_cvt_pk_bf16_f32 %0, %1, %2" : "=v"(d) : "v"(a), "v"(b));
  return d;
}

// ---------------------------------------------------------------------------
// Kernel 1: xw GEMM -> permuted layout (512-elem chunks), bias folded in.
// Staging via packed bf16 converts; A-tile written with b64 stores.
// ---------------------------------------------------------------------------
__global__ __launch_bounds__(256, 4) void xw_gemm(
    const float* __restrict__ inp,       // [32768][512]
    const float* __restrict__ Wf,        // [512][512]
    const float* __restrict__ Wb,        // [512][512]
    const float* __restrict__ bhf,       // [512]
    const float* __restrict__ bhb,       // [512]
    unsigned short* __restrict__ xwpf,   // permuted bf16 (xw + bias)
    unsigned short* __restrict__ xwpb) {
  __shared__ __align__(16) unsigned short As[64 * 40];   // [row][k] pad 40
  __shared__ __align__(16) unsigned short Bfs[64 * 40];  // [n][k] transposed
  __shared__ __align__(16) unsigned short Bbs[64 * 40];
  const int tid = threadIdx.x;
  const int w = tid >> 6, l = tid & 63;
  const int lr = l & 15, lg = l >> 4;
  const int rbase = blockIdx.x * 64;
  const int nbase = blockIdx.y * 64;

  f32x4 accf[4], accb[4];
#pragma unroll
  for (int tn = 0; tn < 4; ++tn) { accf[tn] = (f32x4){0,0,0,0}; accb[tn] = (f32x4){0,0,0,0}; }

  for (int i = 0; i < 16; ++i) {
    const int k0 = i * 32;
    __syncthreads();
    // stage A (64x32 fp32 -> bf16), packed converts + b64 writes
#pragma unroll
    for (int e = 0; e < 2; ++e) {
      int lin4 = tid + e * 256;               // 0..511 float4s
      int r = lin4 >> 3, c4 = (lin4 & 7) * 4;
      float4 v = *reinterpret_cast<const float4*>(&inp[(rbase + r) * 512 + k0 + c4]);
      uint2 p;
      p.x = cvt_pk_bf16(v.x, v.y);
      p.y = cvt_pk_bf16(v.z, v.w);
      *reinterpret_cast<uint2*>(&As[r * 40 + c4]) = p;
    }
    // stage B transposed [n][k], packed converts (scatter stores stay b16)
#pragma unroll
    for (int e = 0; e < 2; ++e) {
      int lin4 = tid + e * 256;               // 0..511
      int r = lin4 >> 4, c4 = (lin4 & 15) * 4; // r = k row, c4 = n col
      float4 vf = *reinterpret_cast<const float4*>(&Wf[(k0 + r) * 512 + nbase + c4]);
      float4 vb = *reinterpret_cast<const float4*>(&Wb[(k0 + r) * 512 + nbase + c4]);
      unsigned int uf0 = cvt_pk_bf16(vf.x, vf.y);
      unsigned int uf1 = cvt_pk_bf16(vf.z, vf.w);
      unsigned int ub0 = cvt_pk_bf16(vb.x, vb.y);
      unsigned int ub1 = cvt_pk_bf16(vb.z, vb.w);
      Bfs[(c4 + 0) * 40 + r] = (unsigned short)uf0;
      Bfs[(c4 + 1) * 40 + r] = (unsigned short)(uf0 >> 16);
      Bfs[(c4 + 2) * 40 + r] = (unsigned short)uf1;
      Bfs[(c4 + 3) * 40 + r] = (unsigned short)(uf1 >> 16);
      Bbs[(c4 + 0) * 40 + r] = (unsigned short)ub0;
      Bbs[(c4 + 1) * 40 + r] = (unsigned short)(ub0 >> 16);
      Bbs[(c4 + 2) * 40 + r] = (unsigned short)ub1;
      Bbs[(c4 + 3) * 40 + r] = (unsigned short)(ub1 >> 16);
    }
    __syncthreads();
    // compute: wave w owns rows w*16..+16
    const int ar = w * 16 + lr;
    const int kg = lg * 8;
    short8 a = *reinterpret_cast<const short8*>(&As[ar * 40 + kg]);
#pragma unroll
    for (int tn = 0; tn < 4; ++tn) {
      const int bc = tn * 16 + lr;
      short8 bf = *reinterpret_cast<const short8*>(&Bfs[bc * 40 + kg]);
      short8 bb = *reinterpret_cast<const short8*>(&Bbs[bc * 40 + kg]);
      accf[tn] = __builtin_amdgcn_mfma_f32_16x16x32_bf16(a, bf, accf[tn], 0, 0, 0);
      accb[tn] = __builtin_amdgcn_mfma_f32_16x16x32_bf16(a, bb, accb[tn], 0, 0, 0);
    }
  }
  // epilogue -> permuted layout. C frag (tn,q): row = rbase+w*16+lg*4+q,
  // col = nbase+tn*16+lr.  u64 slot = ((bx*4+w)*16 + by*2 + (tn>>1))*128 +
  //                                   (lg*16+lr)*2 + (tn&1)
  unsigned long long* pf = reinterpret_cast<unsigned long long*>(xwpf);
  unsigned long long* pb = reinterpret_cast<unsigned long long*>(xwpb);
  const int b64 = (((int)blockIdx.x * 4 + w) * 16 + (int)blockIdx.y * 2) * 128 +
                  (lg * 16 + lr) * 2;
#pragma unroll
  for (int tn = 0; tn < 4; ++tn) {
    const int colb = nbase + tn * 16 + lr;
    const float bfv = bhf[colb], bbv = bhb[colb];
    unsigned long long vf =
        (unsigned long long)cvt_pk_bf16(accf[tn][0] + bfv, accf[tn][1] + bfv)
      | ((unsigned long long)cvt_pk_bf16(accf[tn][2] + bfv, accf[tn][3] + bfv) << 32);
    unsigned long long vb =
        (unsigned long long)cvt_pk_bf16(accb[tn][0] + bbv, accb[tn][1] + bbv)
      | ((unsigned long long)cvt_pk_bf16(accb[tn][2] + bbv, accb[tn][3] + bbv) << 32);
    pf[b64 + (tn >> 1) * 128 + (tn & 1)] = vf;
    pb[b64 + (tn >> 1) * 128 + (tn & 1)] = vb;
  }
}

// ---------------------------------------------------------------------------
// Kernel 2: CU-local scan, 8 WGs x 1024 threads (16 waves, 4/SIMD).
// Wave w owns cols [w*32, w*32+32): 2 n-chains, wq = 64 VGPR.
// (r12 verbatim -- barrier version, 659us proven)
// ---------------------------------------------------------------------------
__global__ __launch_bounds__(1024) void birnn_scan(
    const float* __restrict__ Whf, const float* __restrict__ Whb,
    unsigned short* __restrict__ xwpf, unsigned short* __restrict__ xwpb,
    float* __restrict__ out) {
  const int bid = blockIdx.x;         // 0..7
  const int d  = bid >> 2;
  const int rg = bid & 3;
  const int tid = threadIdx.x;
  const int w = tid >> 6, l = tid & 63;      // w 0..15
  const int lr = l & 15, lg = l >> 4;
  const int cbase = w * 32;
  const int rbase = rg * 16;

  const float* Wh = d ? Whb : Whf;
  unsigned short* xwp = d ? xwpb : xwpf;

  // h ping-pong, fragment-major i8: addr(row,k) = (k>>4)*256 + row*16 + (k&15)
  __shared__ __align__(16) signed char hq[2][8192];

  // preload + quantize W_hh B-frags (k-bijection: k = kk*64 + lg*16 + j)
  const float sW = 127.0f / 0.06f;
  i32x4 wq[2][8];
#pragma unroll
  for (int n = 0; n < 2; ++n) {
    const int col = cbase + n * 16 + lr;
#pragma unroll
    for (int kk = 0; kk < 8; ++kk) {
      i32x4 v;
#pragma unroll
      for (int dw = 0; dw < 4; ++dw) {
        unsigned int pack = 0;
#pragma unroll
        for (int jj = 0; jj < 4; ++jj) {
          const int k = kk * 64 + lg * 16 + dw * 4 + jj;
          float wv = Wh[k * 512 + col] * sW;
          wv = fminf(fmaxf(wv, -127.f), 127.f);
          int q = (int)rintf(wv);
          pack |= ((unsigned int)(q & 0xff)) << (8 * jj);
        }
        v[dw] = (int)pack;
      }
      wq[n][kk] = v;
    }
  }
  const float inv_s = 1.0f / (127.0f * sW);

  // depth-2 prefetch buffers: one short8 (16B) per step
  short8 xA, xB;
  {
    const int t0 = d ? 511 : 0;
    xA = *reinterpret_cast<const short8*>(
        xwp + (((t0 * 4 + rg) * 16 + w) << 9) + (l << 3));
  }
  {
    const int t1 = d ? 510 : 1;
    xB = *reinterpret_cast<const short8*>(
        xwp + (((t1 * 4 + rg) * 16 + w) << 9) + (l << 3));
  }

  uint4 HP;   // packed bf16 h of previous step (8 values)

#define EPI(N, ACC, U0, U1, FINAL_)                                           \
  {                                                                           \
    float h0_ = tanh_cheap(fmaf((float)(ACC)[0], inv_s, bf2f((unsigned short)X[(N)*4+0]))); \
    float h1_ = tanh_cheap(fmaf((float)(ACC)[1], inv_s, bf2f((unsigned short)X[(N)*4+1]))); \
    float h2_ = tanh_cheap(fmaf((float)(ACC)[2], inv_s, bf2f((unsigned short)X[(N)*4+2]))); \
    float h3_ = tanh_cheap(fmaf((float)(ACC)[3], inv_s, bf2f((unsigned short)X[(N)*4+3]))); \
    signed char* hd_ = &hq[buf_][(w * 2 + (N)) * 256 + lg * 64 + lr];         \
    hd_[0]  = (signed char)(int)rintf(h0_ * 127.f);                           \
    hd_[16] = (signed char)(int)rintf(h1_ * 127.f);                           \
    hd_[32] = (signed char)(int)rintf(h2_ * 127.f);                           \
    hd_[48] = (signed char)(int)rintf(h3_ * 127.f);                           \
    U0 = cvt_pk_bf16(h0_, h1_);                                               \
    U1 = cvt_pk_bf16(h2_, h3_);                                               \
    if (FINAL_) {                                                             \
      float* fo_ = out + 33554432 + d * 32768 + (rbase + lg * 4) * 512 +      \
                   cbase + (N) * 16 + lr;                                     \
      fo_[0] = h0_; fo_[512] = h1_; fo_[1024] = h2_; fo_[1536] = h3_;         \
    }                                                                         \
  }

#define STEP(S, XARG, FINAL_)                                                 \
  do {                                                                        \
    const int s_ = (S);                                                       \
    const int t_ = d ? (511 - s_) : s_;                                       \
    const int buf_ = s_ & 1;                                                  \
    const int pb_ = (s_ - 1) & 1;                                             \
    short8& X = (XARG);                                                       \
    { /* deferred global store of h(s-1), overlaps MFMA window */             \
      const int tp_ = d ? (t_ + 1) : (t_ - 1);                                \
      unsigned short* pw_ = xwp + (((tp_ * 4 + rg) * 16 + w) << 9) + (l << 3);\
      *reinterpret_cast<uint4*>(pw_) = HP;                                    \
    }                                                                         \
    i32x4 acc0 = (i32x4){0,0,0,0}, acc1 = (i32x4){0,0,0,0};                   \
    __builtin_amdgcn_s_setprio(1);                                            \
    { /* A-frag window kk=0..3: chunks (kk*4+lg)*256 */                       \
      const signed char* hb_ = &hq[pb_][lg * 256 + lr * 16];                  \
      i32x4 a0 = *(const i32x4*)(hb_ + 0);                                    \
      i32x4 a1 = *(const i32x4*)(hb_ + 1024);                                 \
      i32x4 a2 = *(const i32x4*)(hb_ + 2048);                                 \
      i32x4 a3 = *(const i32x4*)(hb_ + 3072);                                 \
      acc0 = __builtin_amdgcn_mfma_i32_16x16x64_i8(a0, wq[0][0], acc0, 0, 0, 0); \
      acc1 = __builtin_amdgcn_mfma_i32_16x16x64_i8(a0, wq[1][0], acc1, 0, 0, 0); \
      acc0 = __builtin_amdgcn_mfma_i32_16x16x64_i8(a1, wq[0][1], acc0, 0, 0, 0); \
      acc1 = __builtin_amdgcn_mfma_i32_16x16x64_i8(a1, wq[1][1], acc1, 0, 0, 0); \
      acc0 = __builtin_amdgcn_mfma_i32_16x16x64_i8(a2, wq[0][2], acc0, 0, 0, 0); \
      acc1 = __builtin_amdgcn_mfma_i32_16x16x64_i8(a2, wq[1][2], acc1, 0, 0, 0); \
      acc0 = __builtin_amdgcn_mfma_i32_16x16x64_i8(a3, wq[0][3], acc0, 0, 0, 0); \
      acc1 = __builtin_amdgcn_mfma_i32_16x16x64_i8(a3, wq[1][3], acc1, 0, 0, 0); \
    }                                                                         \
    { /* A-frag window kk=4..7 */                                             \
      const signed char* hb_ = &hq[pb_][(16 + lg) * 256 + lr * 16];           \
      i32x4 a0 = *(const i32x4*)(hb_ + 0);                                    \
      i32x4 a1 = *(const i32x4*)(hb_ + 1024);                                 \
      i32x4 a2 = *(const i32x4*)(hb_ + 2048);                                 \
      i32x4 a3 = *(const i32x4*)(hb_ + 3072);                                 \
      acc0 = __builtin_amdgcn_mfma_i32_16x16x64_i8(a0, wq[0][4], acc0, 0, 0, 0); \
      acc1 = __builtin_amdgcn_mfma_i32_16x16x64_i8(a0, wq[1][4], acc1, 0, 0, 0); \
      acc0 = __builtin_amdgcn_mfma_i32_16x16x64_i8(a1, wq[0][5], acc0, 0, 0, 0); \
      acc1 = __builtin_amdgcn_mfma_i32_16x16x64_i8(a1, wq[1][5], acc1, 0, 0, 0); \
      acc0 = __builtin_amdgcn_mfma_i32_16x16x64_i8(a2, wq[0][6], acc0, 0, 0, 0); \
      acc1 = __builtin_amdgcn_mfma_i32_16x16x64_i8(a2, wq[1][6], acc1, 0, 0, 0); \
      acc0 = __builtin_amdgcn_mfma_i32_16x16x64_i8(a3, wq[0][7], acc0, 0, 0, 0); \
      acc1 = __builtin_amdgcn_mfma_i32_16x16x64_i8(a3, wq[1][7], acc1, 0, 0, 0); \
    }                                                                         \
    __builtin_amdgcn_s_setprio(0);                                            \
    EPI(0, acc0, HP.x, HP.y, FINAL_);                                         \
    EPI(1, acc1, HP.z, HP.w, FINAL_);                                         \
    { /* prefetch xw for step s+2 into X */                                   \
      const int tp2_ = d ? (t_ - 2) : (t_ + 2);                               \
      X = *reinterpret_cast<const short8*>(                                   \
          xwp + (((tp2_ * 4 + rg) * 16 + w) << 9) + (l << 3));                \
    }                                                                         \
    lds_barrier();                                                            \
  } while (0)

  // step 0: h0 = 0 -> acc = 0, no MFMA, no deferred store
  {
    const int t_ = d ? 511 : 0;
    const int buf_ = 0;
    short8& X = xA;
    i32x4 z_ = (i32x4){0, 0, 0, 0};
    EPI(0, z_, HP.x, HP.y, 0);
    EPI(1, z_, HP.z, HP.w, 0);
    {
      const int tp2_ = d ? (t_ - 2) : (t_ + 2);
      xA = *reinterpret_cast<const short8*>(
          xwp + (((tp2_ * 4 + rg) * 16 + w) << 9) + (l << 3));
    }
    lds_barrier();
  }

  for (int ss = 0; ss < 255; ++ss) {
    STEP(1 + 2 * ss, xB, 0);
    STEP(2 + 2 * ss, xA, 0);
  }
  STEP(511, xB, 1);

  // store h(511)
  {
    const int tl_ = d ? 0 : 511;
    unsigned short* pw_ = xwp + (((tl_ * 4 + rg) * 16 + w) << 9) + (l << 3);
    *reinterpret_cast<uint4*>(pw_) = HP;
  }
#undef STEP
#undef EPI
}

// ---------------------------------------------------------------------------
// Kernel 3: expand h (bf16, permuted) -> fp32 outputs. (unchanged)
// slot(t,b,col) = ((t*4+(b>>4))*16 + (col>>5))*512 +
//                 (((b>>2)&3)*16 + (col&15))*8 + ((col>>4)&1)*4 + (b&3)
// ---------------------------------------------------------------------------
__global__ __launch_bounds__(1024) void expand_out(
    const unsigned short* __restrict__ xwpf,
    const unsigned short* __restrict__ xwpb,
    float* __restrict__ out) {
  const int g = blockIdx.x * 1024 + threadIdx.x;   // 8,388,608 threads
  const int flat = g * 4;                          // 4 consecutive out elems
  const int row = flat >> 10;                      // t*64 + b
  const int c   = flat & 1023;
  const int t = row >> 6, b = row & 63;
  const int d = c >> 9, col = c & 511;
  const unsigned short* buf = d ? xwpb : xwpf;
  const int lr0 = col & 15;                        // 4-aligned, <=12
  const int base = ((t * 4 + (b >> 4)) * 16 + (col >> 5)) * 512 +
                   (((b >> 2) & 3) * 16) * 8 + ((col >> 4) & 1) * 4 + (b & 3);
  float4 v;
  v.x = bf2f(buf[base + (lr0 + 0) * 8]);
  v.y = bf2f(buf[base + (lr0 + 1) * 8]);
  v.z = bf2f(buf[base + (lr0 + 2) * 8]);
  v.w = bf2f(buf[base + (lr0 + 3) * 8]);
  *reinterpret_cast<float4*>(out + flat) = v;
}

// ---------------------------------------------------------------------------
extern "C" void kernel_launch(void* const* d_in, const int* in_sizes, int n_in,
                              void* d_out, int out_size, void* d_ws, size_t ws_size,
                              hipStream_t stream) {
  (void)in_sizes; (void)n_in; (void)out_size; (void)ws_size;
  const float* inputs = (const float*)d_in[0];
  const float* W_xh_f = (const float*)d_in[1];
  const float* W_hh_f = (const float*)d_in[2];
  const float* b_h_f  = (const float*)d_in[3];
  const float* W_xh_b = (const float*)d_in[4];
  const float* W_hh_b = (const float*)d_in[5];
  const float* b_h_b  = (const float*)d_in[6];

  // ws: [xwpf 16.78M elems][pad 64K elems][xwpb 16.78M elems][pad]  (bf16)
  // pads absorb depth-2 prefetch overruns (fwd t+2<=513; bwd t-2>=-2 reads
  // land in xwpf's pad region).
  unsigned short* xwpf = (unsigned short*)d_ws;
  unsigned short* xwpb = xwpf + 16777216 + 65536;

  dim3 g1(512, 8), b1(256);
  xw_gemm<<<g1, b1, 0, stream>>>(inputs, W_xh_f, W_xh_b, b_h_f, b_h_b, xwpf, xwpb);

  birnn_scan<<<dim3(8), dim3(1024), 0, stream>>>(
      W_hh_f, W_hh_b, xwpf, xwpb, (float*)d_out);

  expand_out<<<dim3(8192), dim3(1024), 0, stream>>>(xwpf, xwpb, (float*)d_out);
}